// Round 1
// baseline (156.007 us; speedup 1.0000x reference)
//
#include <hip/hip_runtime.h>

// Types
typedef _Float16 half8 __attribute__((ext_vector_type(8)));
typedef _Float16 half2v __attribute__((ext_vector_type(2)));
typedef short    s16x8 __attribute__((ext_vector_type(8)));
typedef float    f32x4 __attribute__((ext_vector_type(4)));

#define LL 256
#define DD 64
#define BB 32
#define LREL 0.01f
#define EMBC (LL*DD + 1)   // 16385

// ---------------- prep: y16 = (emb[:, :-1]*tw) as f16, mask rows ----------------
__global__ void k_prep(const float* __restrict__ emb, const float* __restrict__ tw,
                       _Float16* __restrict__ y16, float* __restrict__ maskw)
{
    int lin  = blockIdx.x * 4 + (threadIdx.x >> 6);   // one wave per (b,l)
    int lane = threadIdx.x & 63;
    int b = lin >> 8, l = lin & 255;
    float e = emb[(size_t)b * EMBC + l * 64 + lane];
    float t = tw[l * 64 + lane];
    y16[((size_t)(b * 256 + l)) * 64 + lane] = (_Float16)(e * t);
    float a = fabsf(e);
    #pragma unroll
    for (int m = 32; m; m >>= 1) a += __shfl_xor(a, m, 64);
    if (lane == 0) maskw[b * 256 + l] = (a > 0.f) ? 1.f : 0.f;
}

// ---------------- prep: weights to f16 ----------------
__global__ void k_prepw(const float* __restrict__ w1, const float* __restrict__ w2,
                        _Float16* __restrict__ w1h, _Float16* __restrict__ w2h)
{
    int idx = blockIdx.x * 256 + threadIdx.x;
    if (idx < 8192)       w1h[idx] = (_Float16)w1[idx];
    else if (idx < 9216)  w2h[idx - 8192] = (_Float16)w2[idx - 8192];
}

// ---------------- x1 = emb @ tw + tb, and zero bsum ----------------
__global__ void k_x1(const float* __restrict__ emb, const float* __restrict__ tw,
                     const float* __restrict__ tb, float* __restrict__ x1ws,
                     float* __restrict__ bsum)
{
    int b = blockIdx.x, tid = threadIdx.x;
    const float* row = emb + (size_t)b * EMBC;
    float part = 0.f;
    for (int c = tid; c < EMBC; c += 256) part = fmaf(row[c], tw[c], part);
    __shared__ float red[256];
    red[tid] = part; __syncthreads();
    for (int s = 128; s; s >>= 1) { if (tid < s) red[tid] += red[tid + s]; __syncthreads(); }
    if (tid == 0) { x1ws[b] = red[0] + tb[0]; bsum[b] = 0.f; }
}

// ---------------- main: fused pairwise MLP + triu-masked sum ----------------
// Block: 256 thr = 4 waves. Block tile: 16 i-rows x 64 j-cols; wave w owns j-strip w*16..w*16+15.
// Per (i, 16-j) wave-tile: feat frags in packed f16, 16 MFMA (layer1 K=128, 4 d-tiles),
// h1 via per-wave LDS scratch, 2 MFMA (layer2), epilogue dot w3 + mask + triu.
__global__ __launch_bounds__(256, 2) void k_main(
    const _Float16* __restrict__ y16, const float* __restrict__ maskw,
    const _Float16* __restrict__ w1h, const _Float16* __restrict__ w2h,
    const float* __restrict__ b1, const float* __restrict__ b2,
    const float* __restrict__ w3, const float* __restrict__ b3,
    float* __restrict__ bsum)
{
    const int tid = threadIdx.x;
    const int lane = tid & 63, wid = tid >> 6;
    const int g = lane >> 4, p = lane & 15;

    int blk = blockIdx.x;
    int batch = blk / 40;
    int t = blk % 40;
    int bi, bj;            // upper-triangle super-blocks: bj=0..3 has 4*(bj+1) bi's
    if (t < 4)       { bj = 0; bi = t; }
    else if (t < 12) { bj = 1; bi = t - 4; }
    else if (t < 24) { bj = 2; bi = t - 12; }
    else             { bj = 3; bi = t - 24; }
    const int i0 = bi * 16, j0 = bj * 64;

    __shared__ _Float16 yi_s[16][72];       // 144B rows: 16B-aligned reads, 4-bank row shift
    __shared__ _Float16 yj_s[64][72];
    __shared__ _Float16 h1_s[4][16][72];    // per-wave scratch, no cross-wave sharing
    __shared__ float mi_s[16];
    __shared__ float mj_s[64];

    const _Float16* ybase = y16 + (size_t)batch * (LL * DD);
    for (int r = tid; r < 80 * 8; r += 256) {       // 80 rows x 8 chunks of 16B
        int row = r >> 3, c = r & 7;
        if (row < 16)
            *(float4*)&yi_s[row][c * 8] = *(const float4*)(ybase + (i0 + row) * 64 + c * 8);
        else {
            int rr = row - 16;
            *(float4*)&yj_s[rr][c * 8] = *(const float4*)(ybase + (j0 + rr) * 64 + c * 8);
        }
    }
    if (tid < 16) mi_s[tid] = maskw[batch * LL + i0 + tid];
    if (tid < 64) mj_s[tid] = maskw[batch * LL + j0 + tid];
    __syncthreads();

    // Per-lane constant fragments. k-mapping f = kb*32 + g*8 + j used consistently
    // for BOTH A and B operands (any consistent bijection over k-slots is valid).
    half8 w1f[4][4];
    #pragma unroll
    for (int T = 0; T < 4; ++T)
        #pragma unroll
        for (int kb = 0; kb < 4; ++kb)
            w1f[T][kb] = *(const half8*)(w1h + (T * 16 + p) * 128 + kb * 32 + g * 8);
    half8 w2f[2];
    #pragma unroll
    for (int kb = 0; kb < 2; ++kb)
        w2f[kb] = *(const half8*)(w2h + p * 64 + kb * 32 + g * 8);

    f32x4 b1v[4];
    #pragma unroll
    for (int T = 0; T < 4; ++T) b1v[T] = *(const f32x4*)(b1 + T * 16 + g * 4);
    f32x4 b2v = *(const f32x4*)(b2 + g * 4);
    f32x4 w3v = *(const f32x4*)(w3 + g * 4);
    const float b3v = (g == 0) ? b3[0] : 0.f;   // add b3 once per pair (group 0 only)

    const int jl = wid * 16 + p;
    const int jglob = j0 + jl;
    const float mj = mj_s[jl];
    const half8 yjA = *(const half8*)&yj_s[jl][g * 8];
    const half8 yjB = *(const half8*)&yj_s[jl][32 + g * 8];
    const int jmax = j0 + wid * 16 + 15;

    float sacc = 0.f;
    const _Float16 h05 = (_Float16)0.5f;

    for (int il = 0; il < 16; ++il) {
        const int i = i0 + il;
        if (jmax <= i) continue;    // whole 16-pair tile in lower triangle

        const half8 yiA = *(const half8*)&yi_s[il][g * 8];
        const half8 yiB = *(const half8*)&yi_s[il][32 + g * 8];

        half8 f0 = (yiA + yjA) * h05;           // feat[0:32)   sum-half
        half8 f1 = (yiB + yjB) * h05;           // feat[32:64)
        s16x8 ad0 = __builtin_bit_cast(s16x8, yiA - yjA) & (short)0x7FFF;
        s16x8 ad1 = __builtin_bit_cast(s16x8, yiB - yjB) & (short)0x7FFF;
        half8 f2 = __builtin_bit_cast(half8, ad0);   // feat[64:96)  |diff|
        half8 f3 = __builtin_bit_cast(half8, ad1);   // feat[96:128)

        f32x4 acc[4] = {};
        #pragma unroll
        for (int T = 0; T < 4; ++T) {
            acc[T] = __builtin_amdgcn_mfma_f32_16x16x32_f16(w1f[T][0], f0, acc[T], 0, 0, 0);
            acc[T] = __builtin_amdgcn_mfma_f32_16x16x32_f16(w1f[T][1], f1, acc[T], 0, 0, 0);
            acc[T] = __builtin_amdgcn_mfma_f32_16x16x32_f16(w1f[T][2], f2, acc[T], 0, 0, 0);
            acc[T] = __builtin_amdgcn_mfma_f32_16x16x32_f16(w1f[T][3], f3, acc[T], 0, 0, 0);
        }

        // epilogue 1: D layout col=pair=p, row=d=T*16+g*4+r (HW-verified C/D map)
        #pragma unroll
        for (int T = 0; T < 4; ++T) {
            float h0 = acc[T][0] + b1v[T][0];
            float h1 = acc[T][1] + b1v[T][1];
            float h2 = acc[T][2] + b1v[T][2];
            float h3 = acc[T][3] + b1v[T][3];
            h0 = fmaxf(h0, 0.f) + LREL * fminf(h0, 0.f);
            h1 = fmaxf(h1, 0.f) + LREL * fminf(h1, 0.f);
            h2 = fmaxf(h2, 0.f) + LREL * fminf(h2, 0.f);
            h3 = fmaxf(h3, 0.f) + LREL * fminf(h3, 0.f);
            half2v p01, p23;
            p01[0] = (_Float16)h0; p01[1] = (_Float16)h1;
            p23[0] = (_Float16)h2; p23[1] = (_Float16)h3;
            *(half2v*)&h1_s[wid][p][T * 16 + g * 4]     = p01;
            *(half2v*)&h1_s[wid][p][T * 16 + g * 4 + 2] = p23;
        }

        const half8 hB0 = *(const half8*)&h1_s[wid][p][g * 8];
        const half8 hB1 = *(const half8*)&h1_s[wid][p][32 + g * 8];
        f32x4 acc2 = {};
        acc2 = __builtin_amdgcn_mfma_f32_16x16x32_f16(w2f[0], hB0, acc2, 0, 0, 0);
        acc2 = __builtin_amdgcn_mfma_f32_16x16x32_f16(w2f[1], hB1, acc2, 0, 0, 0);

        float sp = b3v;
        #pragma unroll
        for (int r = 0; r < 4; ++r) {
            float h = acc2[r] + b2v[r];
            h = fmaxf(h, 0.f) + LREL * fminf(h, 0.f);
            sp += h * w3v[r];
        }
        const float mfac = (jglob > i) ? (mi_s[il] * mj) : 0.f;
        sacc += sp * mfac;
    }

    #pragma unroll
    for (int m = 32; m; m >>= 1) sacc += __shfl_xor(sacc, m, 64);
    if (lane == 0) atomicAdd(&bsum[batch], sacc);
}

// ---------------- finalize ----------------
__global__ void k_fin(const float* __restrict__ x1ws, const float* __restrict__ bsum,
                      const float* __restrict__ scale, float* __restrict__ out)
{
    int t = threadIdx.x;
    if (t < BB) out[t] = x1ws[t] + bsum[t] * scale[0];
}

extern "C" void kernel_launch(void* const* d_in, const int* in_sizes, int n_in,
                              void* d_out, int out_size, void* d_ws, size_t ws_size,
                              hipStream_t stream)
{
    const float* emb   = (const float*)d_in[0];
    const float* tw    = (const float*)d_in[1];
    const float* tb    = (const float*)d_in[2];
    const float* w1    = (const float*)d_in[3];
    const float* b1    = (const float*)d_in[4];
    const float* w2    = (const float*)d_in[5];
    const float* b2    = (const float*)d_in[6];
    const float* w3    = (const float*)d_in[7];
    const float* b3    = (const float*)d_in[8];
    const float* scale = (const float*)d_in[9];

    char* ws = (char*)d_ws;
    _Float16* y16 = (_Float16*)(ws + 0);          // 1,048,576 B
    float*    maskw = (float*)(ws + 1048576);     //    32,768 B
    _Float16* w1h  = (_Float16*)(ws + 1081344);   //    16,384 B
    _Float16* w2h  = (_Float16*)(ws + 1097728);   //     2,048 B
    float*    x1ws = (float*)(ws + 1099776);      //       128 B
    float*    bsum = (float*)(ws + 1099904);      //       128 B
    float*    out  = (float*)d_out;

    hipLaunchKernelGGL(k_prep,  dim3(2048), dim3(256), 0, stream, emb, tw, y16, maskw);
    hipLaunchKernelGGL(k_prepw, dim3(36),   dim3(256), 0, stream, w1, w2, w1h, w2h);
    hipLaunchKernelGGL(k_x1,    dim3(32),   dim3(256), 0, stream, emb, tw, tb, x1ws, bsum);
    hipLaunchKernelGGL(k_main,  dim3(1280), dim3(256), 0, stream, y16, maskw, w1h, w2h,
                       b1, b2, w3, b3, bsum);
    hipLaunchKernelGGL(k_fin,   dim3(1),    dim3(64),  0, stream, x1ws, bsum, scale, out);
}

// Round 11
// 154.086 us; speedup vs baseline: 1.0125x; 1.0125x over previous
//
#include <hip/hip_runtime.h>

typedef _Float16 half8  __attribute__((ext_vector_type(8)));
typedef _Float16 half2v __attribute__((ext_vector_type(2)));
typedef short    s16x8  __attribute__((ext_vector_type(8)));
typedef float    f32x4  __attribute__((ext_vector_type(4)));

#define LL 256
#define DD 64
#define BB 32
#define LREL 0.01f
#define EMBC (LL*DD + 1)       // 16385
#define NTILE 72               // per-batch 16i x 32j upper-tri tiles
#define NBLK_MAIN (BB * NTILE) // 2304

// ---------------- fused prep: y16(=emb*tw*0.5), mask, f16 weights, x1 partials, zero accum ----
__global__ void k_prep_all(const float* __restrict__ emb, const float* __restrict__ tw,
                           const float* __restrict__ w1, const float* __restrict__ w2,
                           _Float16* __restrict__ y16, float* __restrict__ maskw,
                           _Float16* __restrict__ w1h, _Float16* __restrict__ w2h,
                           float* __restrict__ x1part, float* __restrict__ bc)
{
    int blk = blockIdx.x, tid = threadIdx.x;
    if (blk < 2048) {
        // one wave per (b,l): y = emb*tw*0.5 in f16; mask row
        int lin = blk * 4 + (tid >> 6);
        int lane = tid & 63;
        int b = lin >> 8, l = lin & 255;
        float e = emb[(size_t)b * EMBC + l * 64 + lane];
        float t = tw[l * 64 + lane];
        y16[((size_t)(b * 256 + l)) * 64 + lane] = (_Float16)(e * t * 0.5f);
        float a = fabsf(e);
        #pragma unroll
        for (int m = 32; m; m >>= 1) a += __shfl_xor(a, m, 64);
        if (lane == 0) maskw[b * 256 + l] = (a > 0.f) ? 1.f : 0.f;
    } else if (blk < 2084) {
        int idx = (blk - 2048) * 256 + tid;
        if (idx < 8192) {
            float v = w1[idx];
            if ((idx & 127) >= 64) v *= 2.f;   // fold the |diff|*2 (y stored halved)
            w1h[idx] = (_Float16)v;
        } else if (idx < 9216) {
            w2h[idx - 8192] = (_Float16)w2[idx - 8192];
        }
        if (blk == 2048 && tid < 33) bc[tid] = 0.f;   // bsum[32] + counter
    } else {
        // x1 partials: 4 blocks per batch, no atomics/pre-zero needed
        int bl = blk - 2084;
        int b = bl >> 2, q = bl & 3;
        const float* row = emb + (size_t)b * EMBC;
        int cend = (q + 1) * 4097; if (cend > EMBC) cend = EMBC;
        float part = 0.f;
        for (int c = q * 4097 + tid; c < cend; c += 256) part = fmaf(row[c], tw[c], part);
        __shared__ float red[256];
        red[tid] = part; __syncthreads();
        for (int s = 128; s; s >>= 1) { if (tid < s) red[tid] += red[tid + s]; __syncthreads(); }
        if (tid == 0) x1part[bl] = red[0];
    }
}

// ---------------- main: fused pairwise MLP + triu-masked sum + finalize ----------------
// 128 thr = 2 waves; tile 16i x 32j; wave w owns j-strip [j0+16w, j0+16w+16).
// layer1->layer2 redistribution via per-wave LDS scratch (R1-proven layout).
__global__ __launch_bounds__(128) void k_main(
    const _Float16* __restrict__ y16, const float* __restrict__ maskw,
    const _Float16* __restrict__ w1h, const _Float16* __restrict__ w2h,
    const float* __restrict__ b1, const float* __restrict__ b2,
    const float* __restrict__ w3, const float* __restrict__ b3,
    const float* __restrict__ x1part, const float* __restrict__ tb,
    const float* __restrict__ scale, float* __restrict__ bc,
    float* __restrict__ out)
{
    const int tid = threadIdx.x;
    const int lane = tid & 63, wid = tid >> 6;
    const int g = lane >> 4, p = lane & 15;

    const int blk = blockIdx.x;
    const int batch = blk / NTILE;
    const int t = blk - batch * NTILE;
    int bj, bi;   // cumulative tile counts {0,2,6,12,20,30,42,56,72}
    if (t < 12)      { if (t < 2) { bj = 0; bi = t; } else if (t < 6) { bj = 1; bi = t - 2; } else { bj = 2; bi = t - 6; } }
    else if (t < 30) { if (t < 20) { bj = 3; bi = t - 12; } else { bj = 4; bi = t - 20; } }
    else             { if (t < 42) { bj = 5; bi = t - 30; } else if (t < 56) { bj = 6; bi = t - 42; } else { bj = 7; bi = t - 56; } }
    const int i0 = bi * 16, j0 = bj * 32;

    __shared__ _Float16 yi_s[16][72];   // 144B rows (16B-aligned chunks)
    __shared__ _Float16 yj_s[32][72];
    __shared__ _Float16 h1_s[2][16][72];   // per-wave scratch, no cross-wave sharing
    __shared__ float mi_s[16], mj_s[32];
    __shared__ int lastflag;

    const _Float16* ybase = y16 + (size_t)batch * (LL * DD);
    for (int r = tid; r < 48 * 8; r += 128) {
        int row = r >> 3, c = r & 7;
        int pos = (row < 16) ? (i0 + row) : (j0 + row - 16);
        float4 v = *(const float4*)(ybase + pos * 64 + c * 8);
        if (row < 16) *(float4*)&yi_s[row][c * 8] = v;
        else          *(float4*)&yj_s[row - 16][c * 8] = v;
    }
    if (tid < 16)      mi_s[tid]      = maskw[batch * LL + i0 + tid];
    else if (tid < 48) mj_s[tid - 16] = maskw[batch * LL + j0 + tid - 16];
    __syncthreads();

    // constant fragments (k-mapping f = kb*32 + g*8 + e, identical for A and B)
    half8 w1f[4][4];
    #pragma unroll
    for (int T = 0; T < 4; ++T)
        #pragma unroll
        for (int kb = 0; kb < 4; ++kb)
            w1f[T][kb] = *(const half8*)(w1h + (T * 16 + p) * 128 + kb * 32 + g * 8);
    half8 w2f[2];
    #pragma unroll
    for (int kb = 0; kb < 2; ++kb)
        w2f[kb] = *(const half8*)(w2h + p * 64 + kb * 32 + g * 8);

    f32x4 b1v[4];
    #pragma unroll
    for (int T = 0; T < 4; ++T) b1v[T] = *(const f32x4*)(b1 + T * 16 + g * 4);
    const f32x4 b2v = *(const f32x4*)(b2 + g * 4);
    const f32x4 w3v = *(const f32x4*)(w3 + g * 4);
    const float b3v = (g == 0) ? b3[0] : 0.f;

    const int jl = wid * 16 + p;
    const int jglob = j0 + jl;
    const float mj = mj_s[jl];
    const half8 yjA = *(const half8*)&yj_s[jl][g * 8];
    const half8 yjB = *(const half8*)&yj_s[jl][32 + g * 8];

    const int jmax = j0 + wid * 16 + 15;
    int nil = jmax - i0; if (nil > 16) nil = 16;

    const half2v lrel2 = {(_Float16)LREL, (_Float16)LREL};
    const half2v zero2 = {};

    float sacc = 0.f;
    for (int il = 0; il < nil; ++il) {
        const int i = i0 + il;
        const half8 yiA = *(const half8*)&yi_s[il][g * 8];
        const half8 yiB = *(const half8*)&yi_s[il][32 + g * 8];

        half8 f0 = yiA + yjA;                        // (xi+xj)/2
        half8 f1 = yiB + yjB;
        s16x8 ad0 = __builtin_bit_cast(s16x8, yiA - yjA) & (short)0x7FFF;
        s16x8 ad1 = __builtin_bit_cast(s16x8, yiB - yjB) & (short)0x7FFF;
        half8 f2 = __builtin_bit_cast(half8, ad0);   // |xi-xj|/2 (w1 cols pre-doubled)
        half8 f3 = __builtin_bit_cast(half8, ad1);

        f32x4 acc[4] = {b1v[0], b1v[1], b1v[2], b1v[3]};   // bias as C-init
        #pragma unroll
        for (int T = 0; T < 4; ++T) {
            acc[T] = __builtin_amdgcn_mfma_f32_16x16x32_f16(w1f[T][0], f0, acc[T], 0, 0, 0);
            acc[T] = __builtin_amdgcn_mfma_f32_16x16x32_f16(w1f[T][1], f1, acc[T], 0, 0, 0);
            acc[T] = __builtin_amdgcn_mfma_f32_16x16x32_f16(w1f[T][2], f2, acc[T], 0, 0, 0);
            acc[T] = __builtin_amdgcn_mfma_f32_16x16x32_f16(w1f[T][3], f3, acc[T], 0, 0, 0);
        }

        // epilogue 1: pack to f16 + leaky in packed ops; hv[T][q] = rows T*16+g*4+{2q,2q+1}, col p
        #pragma unroll
        for (int T = 0; T < 4; ++T) {
            half2v a = __builtin_bit_cast(half2v, __builtin_amdgcn_cvt_pkrtz(acc[T][0], acc[T][1]));
            half2v b = __builtin_bit_cast(half2v, __builtin_amdgcn_cvt_pkrtz(acc[T][2], acc[T][3]));
            a = __builtin_elementwise_max(a, zero2) + lrel2 * __builtin_elementwise_min(a, zero2);
            b = __builtin_elementwise_max(b, zero2) + lrel2 * __builtin_elementwise_min(b, zero2);
            *(unsigned*)&h1_s[wid][p][T * 16 + g * 4]     = __builtin_bit_cast(unsigned, a);
            *(unsigned*)&h1_s[wid][p][T * 16 + g * 4 + 2] = __builtin_bit_cast(unsigned, b);
        }

        // layer2 B-frag read back (same wave; lgkmcnt ordering only, no barrier)
        const half8 hB0 = *(const half8*)&h1_s[wid][p][g * 8];
        const half8 hB1 = *(const half8*)&h1_s[wid][p][32 + g * 8];

        f32x4 a2 = b2v;                               // bias as C-init
        a2 = __builtin_amdgcn_mfma_f32_16x16x32_f16(w2f[0], hB0, a2, 0, 0, 0);
        a2 = __builtin_amdgcn_mfma_f32_16x16x32_f16(w2f[1], hB1, a2, 0, 0, 0);

        float sp = b3v;
        #pragma unroll
        for (int r = 0; r < 4; ++r) {
            float h = a2[r];
            h = fmaxf(h, 0.f) + LREL * fminf(h, 0.f);
            sp = fmaf(h, w3v[r], sp);
        }
        const float mfac = (jglob > i) ? (mi_s[il] * mj) : 0.f;
        sacc = fmaf(sp, mfac, sacc);
    }

    #pragma unroll
    for (int m = 32; m; m >>= 1) sacc += __shfl_xor(sacc, m, 64);
    if (lane == 0) atomicAdd(&bc[batch], sacc);

    // grid-completion finalize (device-scope atomics; last block writes out)
    __syncthreads();
    if (tid == 0) {
        __threadfence();
        float old = atomicAdd(&bc[32], 1.0f);
        lastflag = (old >= (float)(NBLK_MAIN - 1)) ? 1 : 0;
    }
    __syncthreads();
    if (lastflag && tid < BB) {
        float bs = atomicAdd(&bc[tid], 0.0f);   // coherent read
        float x1 = x1part[tid * 4] + x1part[tid * 4 + 1] + x1part[tid * 4 + 2]
                 + x1part[tid * 4 + 3] + tb[0];
        out[tid] = fmaf(bs, scale[0], x1);
    }
}

extern "C" void kernel_launch(void* const* d_in, const int* in_sizes, int n_in,
                              void* d_out, int out_size, void* d_ws, size_t ws_size,
                              hipStream_t stream)
{
    const float* emb   = (const float*)d_in[0];
    const float* tw    = (const float*)d_in[1];
    const float* tb    = (const float*)d_in[2];
    const float* w1    = (const float*)d_in[3];
    const float* b1    = (const float*)d_in[4];
    const float* w2    = (const float*)d_in[5];
    const float* b2    = (const float*)d_in[6];
    const float* w3    = (const float*)d_in[7];
    const float* b3    = (const float*)d_in[8];
    const float* scale = (const float*)d_in[9];

    char* ws = (char*)d_ws;
    _Float16* y16   = (_Float16*)(ws + 0);         // 1,048,576 B
    float*    maskw = (float*)(ws + 1048576);      //    32,768 B
    _Float16* w1h   = (_Float16*)(ws + 1081344);   //    16,384 B
    _Float16* w2h   = (_Float16*)(ws + 1097728);   //     2,048 B
    float*    x1part= (float*)(ws + 1099776);      //       512 B
    float*    bc    = (float*)(ws + 1100288);      //       136 B (bsum[32]+counter)
    float*    out   = (float*)d_out;

    hipLaunchKernelGGL(k_prep_all, dim3(2048 + 36 + 128), dim3(256), 0, stream,
                       emb, tw, w1, w2, y16, maskw, w1h, w2h, x1part, bc);
    hipLaunchKernelGGL(k_main, dim3(NBLK_MAIN), dim3(128), 0, stream,
                       y16, maskw, w1h, w2h, b1, b2, w3, b3, x1part, tb, scale, bc, out);
}

// Round 13
// 144.399 us; speedup vs baseline: 1.0804x; 1.0671x over previous
//
#include <hip/hip_runtime.h>

typedef _Float16 half8  __attribute__((ext_vector_type(8)));
typedef _Float16 half2v __attribute__((ext_vector_type(2)));
typedef short    s16x8  __attribute__((ext_vector_type(8)));
typedef float    f32x4  __attribute__((ext_vector_type(4)));
typedef int      i32x4  __attribute__((ext_vector_type(4)));

#define LL 256
#define DD 64
#define BB 32
#define LREL 0.01f
#define EMBC (LL*DD + 1)       // 16385
#define NTILE 72               // per-batch 16i x 32j upper-tri tiles
#define NBLK_MAIN (BB * NTILE) // 2304

// ---------------- main: fully fused pairwise MLP, no prep kernel ----------------
// 128 thr = 2 waves; tile 16i x 32j; wave w owns j-strip [j0+16w, j0+16w+16).
// layer1->layer2 entirely in registers: layer2 k-mapping chosen to equal the
// producer's register layout, d(kb,g,e) = (2kb+(e>>2))*16 + g*4 + (e&3).
// Per-block outputs go to distinct part[] slots (no atomics, no zero-init).
__global__ __launch_bounds__(128) void k_main(
    const float* __restrict__ emb, const float* __restrict__ tw,
    const float* __restrict__ w1, const float* __restrict__ b1,
    const float* __restrict__ w2, const float* __restrict__ b2,
    const float* __restrict__ w3, const float* __restrict__ b3,
    float* __restrict__ part)
{
    const int tid = threadIdx.x;
    const int lane = tid & 63, wid = tid >> 6;
    const int g = lane >> 4, p = lane & 15;

    const int blk = blockIdx.x;
    const int batch = blk / NTILE;
    const int t = blk - batch * NTILE;
    int bj, bi;   // cumulative tile counts {2,6,12,20,30,42,56,72}
    if (t < 12)      { if (t < 2) { bj = 0; bi = t; } else if (t < 6) { bj = 1; bi = t - 2; } else { bj = 2; bi = t - 6; } }
    else if (t < 30) { if (t < 20) { bj = 3; bi = t - 12; } else { bj = 4; bi = t - 20; } }
    else             { if (t < 42) { bj = 5; bi = t - 30; } else if (t < 56) { bj = 6; bi = t - 42; } else { bj = 7; bi = t - 56; } }
    const int i0 = bi * 16, j0 = bj * 32;

    __shared__ _Float16 yts[48][72];   // rows 0..15 = i-tile, 16..47 = j-tile (144B rows)
    __shared__ float masks[48];
    __shared__ float wsum[2];

    const float* erow = emb + (size_t)batch * EMBC;

    // row masks from raw emb (sum|emb| > 0), 48 owner-threads, L2-hot rereads
    if (tid < 48) {
        int pos = (tid < 16) ? (i0 + tid) : (j0 + tid - 16);
        const float* r = erow + pos * 64;
        float a = 0.f;
        #pragma unroll 8
        for (int c = 0; c < 64; ++c) a += fabsf(r[c]);
        masks[tid] = (a > 0.f) ? 1.f : 0.f;
    }

    // stage y = emb*tw as f16; wave-per-row (perfect coalescing), scalar f32 loads
    for (int k = 0; k < 24; ++k) {
        int idx = k * 128 + tid;       // 0..3071
        int row = idx >> 6, col = idx & 63;
        int pos = (row < 16) ? (i0 + row) : (j0 + row - 16);
        float e = erow[pos * 64 + col];
        float tt = tw[pos * 64 + col];
        yts[row][col] = (_Float16)(e * tt);
    }

    // w1 fragments from f32 (k-map f = kb*32+g*8+e); fold 0.5 into sum-cols (f<64)
    half8 w1f[4][4];
    #pragma unroll
    for (int T = 0; T < 4; ++T) {
        #pragma unroll
        for (int kb = 0; kb < 4; ++kb) {
            const float* src = w1 + (T * 16 + p) * 128 + kb * 32 + g * 8;
            f32x4 lo = *(const f32x4*)src;
            f32x4 hi = *(const f32x4*)(src + 4);
            const float s = (kb < 2) ? 0.5f : 1.0f;
            half8 h;
            #pragma unroll
            for (int e = 0; e < 4; ++e) {
                h[e]     = (_Float16)(lo[e] * s);
                h[e + 4] = (_Float16)(hi[e] * s);
            }
            w1f[T][kb] = h;
        }
    }
    // w2 fragments with the custom layer-2 k-map d=(2kb+(e>>2))*16+g*4+(e&3)
    half8 w2f[2];
    #pragma unroll
    for (int kb = 0; kb < 2; ++kb) {
        const float* r2 = w2 + p * 64;
        f32x4 lo = *(const f32x4*)(r2 + (2 * kb) * 16 + g * 4);
        f32x4 hi = *(const f32x4*)(r2 + (2 * kb + 1) * 16 + g * 4);
        half8 h;
        #pragma unroll
        for (int e = 0; e < 4; ++e) {
            h[e]     = (_Float16)lo[e];
            h[e + 4] = (_Float16)hi[e];
        }
        w2f[kb] = h;
    }

    f32x4 b1v[4];
    #pragma unroll
    for (int T = 0; T < 4; ++T) b1v[T] = *(const f32x4*)(b1 + T * 16 + g * 4);
    const f32x4 b2v = *(const f32x4*)(b2 + g * 4);
    const f32x4 w3v = *(const f32x4*)(w3 + g * 4);
    const float b3v = (g == 0) ? b3[0] : 0.f;

    __syncthreads();

    const int jl = wid * 16 + p;
    const int jglob = j0 + jl;
    const float mj = masks[16 + jl];
    const half8 yjA = *(const half8*)&yts[16 + jl][g * 8];
    const half8 yjB = *(const half8*)&yts[16 + jl][32 + g * 8];

    const int jmaxv = j0 + wid * 16 + 15;
    int nil = jmaxv - i0; if (nil > 16) nil = 16;

    const half2v lrel2 = {(_Float16)LREL, (_Float16)LREL};
    const half2v zero2 = {};

    float sacc = 0.f;
    for (int il = 0; il < nil; ++il) {
        const int i = i0 + il;
        const half8 yiA = *(const half8*)&yts[il][g * 8];
        const half8 yiB = *(const half8*)&yts[il][32 + g * 8];

        half8 f0 = yiA + yjA;                        // 2*mean (w1 sum-cols pre-halved)
        half8 f1 = yiB + yjB;
        s16x8 ad0 = __builtin_bit_cast(s16x8, yiA - yjA) & (short)0x7FFF;
        s16x8 ad1 = __builtin_bit_cast(s16x8, yiB - yjB) & (short)0x7FFF;
        half8 f2 = __builtin_bit_cast(half8, ad0);   // |xi-xj| exact
        half8 f3 = __builtin_bit_cast(half8, ad1);

        f32x4 acc[4] = {b1v[0], b1v[1], b1v[2], b1v[3]};   // bias as C-init
        #pragma unroll
        for (int T = 0; T < 4; ++T) {
            acc[T] = __builtin_amdgcn_mfma_f32_16x16x32_f16(w1f[T][0], f0, acc[T], 0, 0, 0);
            acc[T] = __builtin_amdgcn_mfma_f32_16x16x32_f16(w1f[T][1], f1, acc[T], 0, 0, 0);
            acc[T] = __builtin_amdgcn_mfma_f32_16x16x32_f16(w1f[T][2], f2, acc[T], 0, 0, 0);
            acc[T] = __builtin_amdgcn_mfma_f32_16x16x32_f16(w1f[T][3], f3, acc[T], 0, 0, 0);
        }

        // pack to f16 + leaky; hv[T][q] = rows T*16+g*4+{2q,2q+1}, col p
        unsigned hv[4][2];
        #pragma unroll
        for (int T = 0; T < 4; ++T) {
            half2v a = __builtin_bit_cast(half2v, __builtin_amdgcn_cvt_pkrtz(acc[T][0], acc[T][1]));
            half2v b = __builtin_bit_cast(half2v, __builtin_amdgcn_cvt_pkrtz(acc[T][2], acc[T][3]));
            a = __builtin_elementwise_max(a, zero2) + lrel2 * __builtin_elementwise_min(a, zero2);
            b = __builtin_elementwise_max(b, zero2) + lrel2 * __builtin_elementwise_min(b, zero2);
            hv[T][0] = __builtin_bit_cast(unsigned, a);
            hv[T][1] = __builtin_bit_cast(unsigned, b);
        }

        // layer-2 B-frag = register concat (custom k-map matches producer layout)
        i32x4 R0 = {(int)hv[0][0], (int)hv[0][1], (int)hv[1][0], (int)hv[1][1]};
        i32x4 R1 = {(int)hv[2][0], (int)hv[2][1], (int)hv[3][0], (int)hv[3][1]};
        half8 hB0 = __builtin_bit_cast(half8, R0);
        half8 hB1 = __builtin_bit_cast(half8, R1);

        f32x4 a2 = b2v;                               // bias as C-init
        a2 = __builtin_amdgcn_mfma_f32_16x16x32_f16(w2f[0], hB0, a2, 0, 0, 0);
        a2 = __builtin_amdgcn_mfma_f32_16x16x32_f16(w2f[1], hB1, a2, 0, 0, 0);

        float sp = b3v;
        #pragma unroll
        for (int r = 0; r < 4; ++r) {
            float h = a2[r];
            h = fmaxf(h, 0.f) + LREL * fminf(h, 0.f);
            sp = fmaf(h, w3v[r], sp);
        }
        const float mfac = (jglob > i) ? (masks[il] * mj) : 0.f;
        sacc = fmaf(sp, mfac, sacc);
    }

    #pragma unroll
    for (int m = 32; m; m >>= 1) sacc += __shfl_xor(sacc, m, 64);
    if (lane == 0) wsum[wid] = sacc;
    __syncthreads();
    if (tid == 0) part[blk] = wsum[0] + wsum[1];
}

// ---------------- finalize: x1 = emb@tw + tb, out = x1 + scale * sum(part) ----------------
__global__ void k_fin(const float* __restrict__ emb, const float* __restrict__ tw,
                      const float* __restrict__ tb, const float* __restrict__ scale,
                      const float* __restrict__ part, float* __restrict__ out)
{
    const int b = blockIdx.x, tid = threadIdx.x;
    const float* row = emb + (size_t)b * EMBC;
    float s = 0.f;
    for (int c = tid; c < EMBC; c += 256) s = fmaf(row[c], tw[c], s);
    if (tid < NTILE) s += scale[0] * part[b * NTILE + tid];
    __shared__ float red[256];
    red[tid] = s; __syncthreads();
    for (int st = 128; st; st >>= 1) { if (tid < st) red[tid] += red[tid + st]; __syncthreads(); }
    if (tid == 0) out[b] = red[0] + tb[0];
}

extern "C" void kernel_launch(void* const* d_in, const int* in_sizes, int n_in,
                              void* d_out, int out_size, void* d_ws, size_t ws_size,
                              hipStream_t stream)
{
    const float* emb   = (const float*)d_in[0];
    const float* tw    = (const float*)d_in[1];
    const float* tb    = (const float*)d_in[2];
    const float* w1    = (const float*)d_in[3];
    const float* b1    = (const float*)d_in[4];
    const float* w2    = (const float*)d_in[5];
    const float* b2    = (const float*)d_in[6];
    const float* w3    = (const float*)d_in[7];
    const float* b3    = (const float*)d_in[8];
    const float* scale = (const float*)d_in[9];

    float* part = (float*)d_ws;          // NBLK_MAIN floats, written before read, no init needed
    float* out  = (float*)d_out;

    hipLaunchKernelGGL(k_main, dim3(NBLK_MAIN), dim3(128), 0, stream,
                       emb, tw, w1, b1, w2, b2, w3, b3, part);
    hipLaunchKernelGGL(k_fin, dim3(BB), dim3(256), 0, stream,
                       emb, tw, tb, scale, part, out);
}